// Round 1
// baseline (1335.764 us; speedup 1.0000x reference)
//
#include <hip/hip_runtime.h>
#include <hip/hip_bf16.h>
#include <math.h>

#define HIDC 64
#define NLAYER 4
#define NG 512
#define M3 768
#define M2 512
#define M1 256
#define NCLS 10
#define EPSV 1e-5f

// ---------------- graph build ----------------
__global__ void k_deg(const int* __restrict__ dst, int E, int* __restrict__ degi){
  int e = blockIdx.x*256 + threadIdx.x;
  if (e < E) atomicAdd(&degi[dst[e]], 1);
}

__global__ void k_norm(const int* __restrict__ degi, float* __restrict__ norm, int n){
  int i = blockIdx.x*256 + threadIdx.x;
  if (i < n){ float d = (float)(degi[i] + 1); norm[i] = rsqrtf(d); }
}

__global__ void k_scan_a(const int* __restrict__ degi, int n, int* __restrict__ row_start, int* __restrict__ bsum){
  __shared__ int tmp[256];
  int tid = threadIdx.x; int i = blockIdx.x*256 + tid;
  int v = (i < n) ? degi[i] : 0;
  tmp[tid] = v; __syncthreads();
  for (int ofs = 1; ofs < 256; ofs <<= 1){
    int t = (tid >= ofs) ? tmp[tid-ofs] : 0;
    __syncthreads();
    tmp[tid] += t;
    __syncthreads();
  }
  if (i < n) row_start[i] = tmp[tid] - v;   // block-local exclusive
  if (tid == 255) bsum[blockIdx.x] = tmp[255];
}

__global__ void k_scan_b(int* __restrict__ bsum, int nb){
  __shared__ int tmp[512];
  int tid = threadIdx.x;
  int v = (tid < nb) ? bsum[tid] : 0;
  tmp[tid] = v; __syncthreads();
  for (int ofs = 1; ofs < 512; ofs <<= 1){
    int t = (tid >= ofs) ? tmp[tid-ofs] : 0;
    __syncthreads();
    tmp[tid] += t;
    __syncthreads();
  }
  if (tid < nb) bsum[tid] = tmp[tid] - v;   // exclusive block offsets
}

__global__ void k_scan_c(int* __restrict__ row_start, const int* __restrict__ bsum,
                         int* __restrict__ cursor, int n, int E){
  int i = blockIdx.x*256 + threadIdx.x;
  if (i < n){
    int v = row_start[i] + bsum[blockIdx.x];
    row_start[i] = v;
    cursor[i] = v;
  }
  if (i == 0) row_start[n] = E;
}

__global__ void k_fill(const int* __restrict__ src, const int* __restrict__ dst, int E,
                       int* __restrict__ cursor, int* __restrict__ col){
  int e = blockIdx.x*256 + threadIdx.x;
  if (e < E){
    int d = dst[e];
    int pos = atomicAdd(&cursor[d], 1);
    col[pos] = src[e];
  }
}

// ---------------- node-level GEMM: U = (A @ W) * norm[row] ----------------
template<int K>
__global__ __launch_bounds__(256) void k_node_gemm(const float* __restrict__ A, int lda,
      const float* __restrict__ W, const float* __restrict__ norm, float* __restrict__ U, int n){
  __shared__ float4 Wl[K*16];   // K x 64 floats
  int tid = threadIdx.x;
  const float4* W4 = (const float4*)W;
  for (int idx = tid; idx < K*16; idx += 256) Wl[idx] = W4[idx];
  __syncthreads();
  int r = blockIdx.x*256 + tid;
  if (r >= n) return;
  float acc[64];
  #pragma unroll
  for (int c = 0; c < 64; c++) acc[c] = 0.f;
  const float* Ar = A + (size_t)r * lda;
  for (int k = 0; k < K; k += 4){
    float4 a4 = *(const float4*)(Ar + k);
    #pragma unroll
    for (int kk = 0; kk < 4; kk++){
      float a = (kk==0) ? a4.x : (kk==1) ? a4.y : (kk==2) ? a4.z : a4.w;
      #pragma unroll
      for (int c4 = 0; c4 < 16; c4++){
        float4 w = Wl[(k+kk)*16 + c4];
        acc[c4*4+0] += a * w.x;
        acc[c4*4+1] += a * w.y;
        acc[c4*4+2] += a * w.z;
        acc[c4*4+3] += a * w.w;
      }
    }
  }
  float nr = norm[r];
  float4* Ur = (float4*)(U + (size_t)r * 64);
  #pragma unroll
  for (int c4 = 0; c4 < 16; c4++){
    Ur[c4] = make_float4(acc[c4*4+0]*nr, acc[c4*4+1]*nr, acc[c4*4+2]*nr, acc[c4*4+3]*nr);
  }
}

// ---------------- aggregation: AGG[i] = norm[i]*(sum_{e->i} U[src] + U[i]) + bias ----------------
__global__ __launch_bounds__(256) void k_agg(const float* __restrict__ U, const int* __restrict__ row_start,
    const int* __restrict__ col, const float* __restrict__ norm, const float* __restrict__ bias,
    float* __restrict__ AGG, int n){
  int tid = threadIdx.x;
  int node = blockIdx.x*4 + (tid >> 6);
  int c = tid & 63;
  if (node >= n) return;
  float s = U[(size_t)node*64 + c];
  int st = row_start[node], en = row_start[node+1];
  for (int k = st; k < en; k++){
    int j = col[k];
    s += U[(size_t)j*64 + c];
  }
  AGG[(size_t)node*64 + c] = norm[node]*s + bias[c];
}

// ---------------- batchnorm over rows ----------------
__global__ void k_bn_stats(const float* __restrict__ AGG, int n, float* __restrict__ sums){
  __shared__ float l1[256], l2[256];
  int tid = threadIdx.x; int c = tid & 63; int grp = tid >> 6;
  float s1 = 0.f, s2 = 0.f;
  for (int r = blockIdx.x*4 + grp; r < n; r += gridDim.x*4){
    float v = AGG[(size_t)r*64 + c];
    s1 += v; s2 += v*v;
  }
  l1[tid] = s1; l2[tid] = s2; __syncthreads();
  if (tid < 64){
    float a1 = l1[tid] + l1[tid+64] + l1[tid+128] + l1[tid+192];
    float a2 = l2[tid] + l2[tid+64] + l2[tid+128] + l2[tid+192];
    atomicAdd(&sums[tid], a1);
    atomicAdd(&sums[64+tid], a2);
  }
}

__global__ void k_bn_finalize(const float* __restrict__ sums, const float* __restrict__ g,
                              const float* __restrict__ b, float* __restrict__ sc,
                              float* __restrict__ sh, float invn){
  int c = threadIdx.x;
  float mean = sums[c]*invn;
  float var = sums[64+c]*invn - mean*mean;
  var = fmaxf(var, 0.f);
  float s = g[c]*rsqrtf(var + EPSV);
  sc[c] = s;
  sh[c] = b[c] - mean*s;
}

__global__ void k_bn_apply(const float* __restrict__ AGG, const float* __restrict__ sc_,
                           const float* __restrict__ sh_, float* __restrict__ H, int n, int slab){
  int idx = blockIdx.x*256 + threadIdx.x;  // over n*16 float4s
  if (idx >= n*16) return;
  int row = idx >> 4, c4 = idx & 15;
  const float4* A4 = (const float4*)AGG;
  const float4* sc4 = (const float4*)sc_;
  const float4* sh4 = (const float4*)sh_;
  float4 v = A4[idx]; float4 s = sc4[c4]; float4 h = sh4[c4];
  float4 o = make_float4(v.x*s.x + h.x, v.y*s.y + h.y, v.z*s.z + h.z, v.w*s.w + h.w);
  ((float4*)H)[(size_t)row*64 + slab*16 + c4] = o;
}

// ---------------- pooling ----------------
__device__ inline int lowerb(const int* a, int n, int key){
  int lo = 0, hi = n;
  while (lo < hi){ int mid = (lo+hi) >> 1; if (a[mid] < key) lo = mid+1; else hi = mid; }
  return lo;
}

__global__ __launch_bounds__(256) void k_pool(const float* __restrict__ H, const int* __restrict__ batch,
                                              int n, float* __restrict__ Hg){
  int g = blockIdx.x; int c = threadIdx.x;
  int st = lowerb(batch, n, g), en = lowerb(batch, n, g+1);
  float s = 0.f, mx = -INFINITY;
  for (int r = st; r < en; r++){
    float v = H[(size_t)r*256 + c];
    s += v; mx = fmaxf(mx, v);
  }
  int cnt = en - st;
  float avg = s / (float)(cnt > 1 ? cnt : 1);
  float mo = (cnt > 0) ? mx : 0.f;
  Hg[(size_t)g*M3 + c]        = avg;
  Hg[(size_t)g*M3 + 256 + c]  = s;
  Hg[(size_t)g*M3 + 512 + c]  = mo;
}

// ---------------- readout BN ----------------
__global__ void k_bn2(const float* __restrict__ Hg, const float* __restrict__ g,
                      const float* __restrict__ b, float* __restrict__ zsc, float* __restrict__ zsh){
  int c = blockIdx.x; int tid = threadIdx.x;  // 64 threads
  float s1 = 0.f, s2 = 0.f;
  for (int r = tid; r < NG; r += 64){
    float v = Hg[(size_t)r*M3 + c];
    s1 += v; s2 += v*v;
  }
  for (int o = 32; o > 0; o >>= 1){ s1 += __shfl_down(s1, o); s2 += __shfl_down(s2, o); }
  if (tid == 0){
    float mean = s1/(float)NG;
    float var = s2/(float)NG - mean*mean;
    var = fmaxf(var, 0.f);
    float sc = g[c]*rsqrtf(var + EPSV);
    zsc[c] = sc;
    zsh[c] = b[c] - mean*sc;
  }
}

__global__ void k_bnapply2(const float* __restrict__ Hg, const float* __restrict__ zsc,
                           const float* __restrict__ zsh, float* __restrict__ Z){
  int idx = blockIdx.x*256 + threadIdx.x;
  if (idx >= NG*M3) return;
  int c = idx % M3;
  Z[idx] = Hg[idx]*zsc[c] + zsh[c];
}

// ---------------- readout GEMMs: row per blockIdx.y, col per thread ----------------
__global__ void k_rowgemm(const float* __restrict__ A, int K, const float* __restrict__ W, int N,
                          const float* __restrict__ bias, float* __restrict__ out, int relu){
  int r = blockIdx.y;
  int c = blockIdx.x*256 + threadIdx.x;
  if (c >= N) return;
  const float* Ar = A + (size_t)r*K;
  float acc = 0.f;
  for (int k = 0; k < K; k += 4){
    float4 a4 = *(const float4*)(Ar + k);
    acc += a4.x * W[(size_t)k*N + c];
    acc += a4.y * W[(size_t)(k+1)*N + c];
    acc += a4.z * W[(size_t)(k+2)*N + c];
    acc += a4.w * W[(size_t)(k+3)*N + c];
  }
  acc += bias[c];
  if (relu) acc = fmaxf(acc, 0.f);
  out[(size_t)r*N + c] = acc;
}

__global__ void k_logsoftmax(const float* __restrict__ Z, float* __restrict__ out){
  int row = blockIdx.x*256 + threadIdx.x;
  if (row >= NG) return;
  float v[NCLS];
  float m = -INFINITY;
  for (int j = 0; j < NCLS; j++){ v[j] = Z[row*NCLS + j]; m = fmaxf(m, v[j]); }
  float s = 0.f;
  for (int j = 0; j < NCLS; j++) s += expf(v[j] - m);
  float ls = logf(s) + m;
  for (int j = 0; j < NCLS; j++) out[row*NCLS + j] = v[j] - ls;
}

// ---------------- host ----------------
extern "C" void kernel_launch(void* const* d_in, const int* in_sizes, int n_in,
                              void* d_out, int out_size, void* d_ws, size_t ws_size,
                              hipStream_t stream){
  const float* x    = (const float*)d_in[0];
  const int*   src  = (const int*)d_in[1];
  const int*   dst  = (const int*)d_in[2];
  const int*   batch= (const int*)d_in[3];
  const float* W0   = (const float*)d_in[4];
  const float* Wsm  = (const float*)d_in[5];
  const float* bsv  = (const float*)d_in[6];
  const float* g_bn = (const float*)d_in[7];
  const float* b_bn = (const float*)d_in[8];
  const float* g_out= (const float*)d_in[9];
  const float* b_out= (const float*)d_in[10];
  const float* w1   = (const float*)d_in[11];
  const float* b1   = (const float*)d_in[12];
  const float* w2   = (const float*)d_in[13];
  const float* b2   = (const float*)d_in[14];
  const float* w3   = (const float*)d_in[15];
  const float* b3   = (const float*)d_in[16];

  int n = in_sizes[3];   // N_NODES (batch vector length)
  int E = in_sizes[1];   // N_EDGES

  char* ws = (char*)d_ws;
  size_t off = 0;
  auto alloc = [&](size_t bytes) -> char* {
    char* p = ws + off;
    off += (bytes + 255) / 256 * 256;
    return p;
  };
  int*   degi      = (int*)  alloc((size_t)n*4);
  float* normv     = (float*)alloc((size_t)n*4);
  int*   row_start = (int*)  alloc((size_t)(n+1)*4);
  int*   cursor    = (int*)  alloc((size_t)n*4);
  int*   colA      = (int*)  alloc((size_t)E*4);
  int*   bsum      = (int*)  alloc(512*4);
  float* U         = (float*)alloc((size_t)n*64*4);
  float* AGG       = (float*)alloc((size_t)n*64*4);
  float* H         = (float*)alloc((size_t)n*256*4);
  float* bnsums    = (float*)alloc(128*4);
  float* bnsc      = (float*)alloc(64*4);
  float* bnsh      = (float*)alloc(64*4);
  float* Hg        = (float*)alloc((size_t)NG*M3*4);
  float* Zbn       = (float*)alloc((size_t)NG*M3*4);
  float* Z1        = (float*)alloc((size_t)NG*M2*4);
  float* Z2        = (float*)alloc((size_t)NG*M1*4);
  float* Z3        = (float*)alloc((size_t)NG*NCLS*4);
  float* zsc       = (float*)alloc(M3*4);
  float* zsh       = (float*)alloc(M3*4);

  int nb256 = (n + 255) / 256;
  int eb256 = (E + 255) / 256;

  hipMemsetAsync(degi, 0, (size_t)n*4, stream);
  k_deg<<<eb256, 256, 0, stream>>>(dst, E, degi);
  k_norm<<<nb256, 256, 0, stream>>>(degi, normv, n);
  k_scan_a<<<nb256, 256, 0, stream>>>(degi, n, row_start, bsum);
  k_scan_b<<<1, 512, 0, stream>>>(bsum, nb256);
  k_scan_c<<<nb256, 256, 0, stream>>>(row_start, bsum, cursor, n, E);
  k_fill<<<eb256, 256, 0, stream>>>(src, dst, E, cursor, colA);

  float invn = 1.f / (float)n;
  for (int l = 0; l < NLAYER; l++){
    if (l == 0)
      k_node_gemm<128><<<nb256, 256, 0, stream>>>(x, 128, W0, normv, U, n);
    else
      k_node_gemm<64><<<nb256, 256, 0, stream>>>(H + (size_t)(l-1)*64, 256,
                                                 Wsm + (size_t)(l-1)*64*64, normv, U, n);
    k_agg<<<(n+3)/4, 256, 0, stream>>>(U, row_start, colA, normv, bsv + l*64, AGG, n);
    hipMemsetAsync(bnsums, 0, 128*4, stream);
    k_bn_stats<<<256, 256, 0, stream>>>(AGG, n, bnsums);
    k_bn_finalize<<<1, 64, 0, stream>>>(bnsums, g_bn + l*64, b_bn + l*64, bnsc, bnsh, invn);
    k_bn_apply<<<(n*16 + 255)/256, 256, 0, stream>>>(AGG, bnsc, bnsh, H, n, l);
  }

  k_pool<<<NG, 256, 0, stream>>>(H, batch, n, Hg);
  k_bn2<<<M3, 64, 0, stream>>>(Hg, g_out, b_out, zsc, zsh);
  k_bnapply2<<<(NG*M3 + 255)/256, 256, 0, stream>>>(Hg, zsc, zsh, Zbn);

  { dim3 g1((M2 + 255)/256, NG); k_rowgemm<<<g1, 256, 0, stream>>>(Zbn, M3, w1, M2, b1, Z1, 1); }
  { dim3 g2((M1 + 255)/256, NG); k_rowgemm<<<g2, 256, 0, stream>>>(Z1, M2, w2, M1, b2, Z2, 1); }
  { dim3 g3(1, NG);              k_rowgemm<<<g3, 256, 0, stream>>>(Z2, M1, w3, NCLS, b3, Z3, 0); }

  k_logsoftmax<<<(NG + 255)/256, 256, 0, stream>>>(Z3, (float*)d_out);
}